// Round 3
// baseline (358.838 us; speedup 1.0000x reference)
//
#include <hip/hip_runtime.h>

// Problem constants (fixed by the reference file)
#define BB 4096
#define FF 16384
#define GG 512
#define SS 32

typedef float v4f __attribute__((ext_vector_type(4)));

// Single-block prep: build v[f] = sum over (g,s) with idx[g,s]==f of
// w[g,s]*fc[g], entirely in LDS (64 KB), then write out. Replaces
// memset + scatter (two dispatches) with one. Handles duplicate idx
// via LDS atomics.
__global__ __launch_bounds__(1024) void prep_kernel(const int* __restrict__ idx,
                                                    const float* __restrict__ w,
                                                    const float* __restrict__ fc,
                                                    float* __restrict__ v) {
    __shared__ float vs[FF];  // exactly 64 KiB
    const int tid = threadIdx.x;
    #pragma unroll
    for (int i = tid; i < FF; i += 1024) vs[i] = 0.0f;
    __syncthreads();
    #pragma unroll
    for (int i = tid; i < GG * SS; i += 1024) {
        int g = i >> 5;  // SS = 32
        atomicAdd(&vs[idx[i]], w[i] * fc[g]);
    }
    __syncthreads();
    #pragma unroll
    for (int i = tid; i < FF; i += 1024) v[i] = vs[i];
}

// GEMV: out[b] = dot(x[b,:], v).  One 256-thread block per row.
// x is streamed exactly once -> nontemporal loads keep L2 free for v.
// Full unroll (16 iters): all 32 loads issued before the FMA chain.
__global__ __launch_bounds__(256) void gemv_kernel(const float* __restrict__ x,
                                                   const float* __restrict__ v,
                                                   float* __restrict__ out) {
    const int b = blockIdx.x;
    const v4f* __restrict__ x4 = (const v4f*)(x + (size_t)b * FF);
    const v4f* __restrict__ v4 = (const v4f*)v;

    v4f acc = {0.0f, 0.0f, 0.0f, 0.0f};
    #pragma unroll
    for (int j = 0; j < (FF / 4) / 256; ++j) {   // 16 iterations
        const int i = threadIdx.x + j * 256;
        v4f xv = __builtin_nontemporal_load(&x4[i]);  // streamed, nt
        v4f vv = v4[i];                               // L1/L2-resident
        acc += xv * vv;
    }
    float sum = (acc.x + acc.y) + (acc.z + acc.w);

    // wave(64)-level shuffle reduction
    #pragma unroll
    for (int off = 32; off > 0; off >>= 1)
        sum += __shfl_down(sum, off, 64);

    __shared__ float wsum[4];
    const int wave = threadIdx.x >> 6;
    if ((threadIdx.x & 63) == 0) wsum[wave] = sum;
    __syncthreads();
    if (threadIdx.x == 0)
        out[b] = wsum[0] + wsum[1] + wsum[2] + wsum[3];
}

extern "C" void kernel_launch(void* const* d_in, const int* in_sizes, int n_in,
                              void* d_out, int out_size, void* d_ws, size_t ws_size,
                              hipStream_t stream) {
    const float* x   = (const float*)d_in[0];   // (B, F) fp32
    const int*   idx = (const int*)d_in[1];     // (G, S) int
    const float* w   = (const float*)d_in[2];   // (G, S) fp32
    const float* fc  = (const float*)d_in[3];   // (G, 1) fp32
    float* out = (float*)d_out;                 // (B, 1) fp32
    float* v   = (float*)d_ws;                  // F fp32 scratch (64 KiB)

    prep_kernel<<<1, 1024, 0, stream>>>(idx, w, fc, v);
    gemv_kernel<<<BB, 256, 0, stream>>>(x, v, out);
}

// Round 4
// 337.289 us; speedup vs baseline: 1.0639x; 1.0639x over previous
//
#include <hip/hip_runtime.h>

// Problem constants (fixed by the reference file)
#define BB 4096
#define FF 16384
#define GG 512
#define SS 32

typedef float v4f __attribute__((ext_vector_type(4)));

// Scatter-add w[g,s]*fc[g] into v[idx[g,s]]. General (handles duplicate
// indices); here idx is a permutation of 0..F-1 so no real contention.
__global__ void build_v_kernel(const int* __restrict__ idx,
                               const float* __restrict__ w,
                               const float* __restrict__ fc,
                               float* __restrict__ v) {
    int i = blockIdx.x * blockDim.x + threadIdx.x;
    if (i < GG * SS) {
        int g = i >> 5;  // SS = 32
        atomicAdd(&v[idx[i]], w[i] * fc[g]);
    }
}

// GEMV: out[b] = dot(x[b,:], v).  One 256-thread block per row.
// x is streamed exactly once -> nontemporal loads keep L2 free for v.
// unroll 8 (not full): balances load-issue depth vs VGPR pressure
// (full 16x unroll regressed: ~128 VGPRs of live load data).
__global__ __launch_bounds__(256) void gemv_kernel(const float* __restrict__ x,
                                                   const float* __restrict__ v,
                                                   float* __restrict__ out) {
    const int b = blockIdx.x;
    const v4f* __restrict__ x4 = (const v4f*)(x + (size_t)b * FF);
    const v4f* __restrict__ v4 = (const v4f*)v;

    // 4 independent accumulator lanes (no serial add chain)
    v4f acc = {0.0f, 0.0f, 0.0f, 0.0f};
    // FF/4 = 4096 v4f elements over 256 threads -> 16 iters/thread
    #pragma unroll 8
    for (int i = threadIdx.x; i < FF / 4; i += 256) {
        v4f xv = __builtin_nontemporal_load(&x4[i]);  // streamed, nt
        v4f vv = v4[i];                               // L1/L2-resident
        acc += xv * vv;
    }
    float sum = (acc.x + acc.y) + (acc.z + acc.w);

    // wave(64)-level shuffle reduction
    #pragma unroll
    for (int off = 32; off > 0; off >>= 1)
        sum += __shfl_down(sum, off, 64);

    __shared__ float wsum[4];
    const int wave = threadIdx.x >> 6;
    if ((threadIdx.x & 63) == 0) wsum[wave] = sum;
    __syncthreads();
    if (threadIdx.x == 0)
        out[b] = wsum[0] + wsum[1] + wsum[2] + wsum[3];
}

extern "C" void kernel_launch(void* const* d_in, const int* in_sizes, int n_in,
                              void* d_out, int out_size, void* d_ws, size_t ws_size,
                              hipStream_t stream) {
    const float* x   = (const float*)d_in[0];   // (B, F) fp32
    const int*   idx = (const int*)d_in[1];     // (G, S) int
    const float* w   = (const float*)d_in[2];   // (G, S) fp32
    const float* fc  = (const float*)d_in[3];   // (G, 1) fp32
    float* out = (float*)d_out;                 // (B, 1) fp32
    float* v   = (float*)d_ws;                  // F fp32 scratch (64 KiB)

    // d_ws is re-poisoned to 0xAA before every timed launch -> zero it here.
    hipMemsetAsync(v, 0, FF * sizeof(float), stream);
    build_v_kernel<<<(GG * SS + 255) / 256, 256, 0, stream>>>(idx, w, fc, v);
    gemv_kernel<<<BB, 256, 0, stream>>>(x, v, out);
}